// Round 8
// baseline (596.539 us; speedup 1.0000x reference)
//
#include <hip/hip_runtime.h>

typedef __bf16 bf16x8 __attribute__((ext_vector_type(8)));
typedef float f32x4 __attribute__((ext_vector_type(4)));

#define MFMA16(a, b, c) __builtin_amdgcn_mfma_f32_16x16x32_bf16(a, b, c, 0, 0, 0)

// async global->LDS, 16B per lane. LDS dest is wave-uniform base; HW writes
// base + lane*16.
__device__ __forceinline__ void gload16(const __bf16* g, __bf16* l) {
    __builtin_amdgcn_global_load_lds(
        (const __attribute__((address_space(1))) void*)g,
        (__attribute__((address_space(3))) void*)l, 16, 0, 0);
}

// channel (1..53) -> region id (0..6); index 0 unused
__constant__ signed char CREG[54] = {
    -1,
    0, 2, 2, 0, 2, 4, 2, 2, 6, 0,   // c=1..10
    4, 5, 2, 4, 6, 6, 4, 4, 6, 4,   // c=11..20
    6, 6, 6, 5, 4, 5, 6, 6, 6, 6,   // c=21..30
    4, 4, 6, 4, 6, 6, 6, 5, 4, 1,   // c=31..40
    6, 4, 6, 3, 4, 3, 1, 6, 3, 3,   // c=41..50
    3, 1, 3                          // c=51..53
};

__device__ __forceinline__ bool mask_ij(int i, int j) {
    if (i >= 60) return j == 0;     // pad rows: keep softmax finite
    if (j >= 60) return false;      // pad cols masked out
    bool ri = i < 7, rj = j < 7;
    if (ri == rj) return true;      // region-region and channel-channel all true
    if (ri) return CREG[j - 6] == i;
    return CREG[i - 6] == j;
}

// ---------------- fused prep: cast x + transpose both weights ----------------
// blocks [0,4096): cast x f32->bf16 (8 elems/thread, grid-stride)
// blocks [4096,4864): transpose+cast qkv_w [1024][3072] -> qwt [3072][1024]
// blocks [4864,5120): transpose+cast out_w [1024][1024] -> owt [1024][1024]
__global__ __launch_bounds__(256) void prep(const float* __restrict__ x,
                                            __bf16* __restrict__ xb,
                                            const float* __restrict__ qkv_w,
                                            __bf16* __restrict__ qwt,
                                            const float* __restrict__ out_w,
                                            __bf16* __restrict__ owt) {
    __shared__ __bf16 t[64][65];
    const int bid = blockIdx.x;
    if (bid < 4096) {
        const int n8 = 31457280 / 8;
        int idx = bid * 256 + threadIdx.x;
        for (int i = idx; i < n8; i += 4096 * 256) {
            f32x4 a = *(const f32x4*)(x + (size_t)i * 8);
            f32x4 b = *(const f32x4*)(x + (size_t)i * 8 + 4);
            bf16x8 v;
            v[0] = (__bf16)a[0]; v[1] = (__bf16)a[1]; v[2] = (__bf16)a[2]; v[3] = (__bf16)a[3];
            v[4] = (__bf16)b[0]; v[5] = (__bf16)b[1]; v[6] = (__bf16)b[2]; v[7] = (__bf16)b[3];
            *(bf16x8*)(xb + (size_t)i * 8) = v;
        }
        return;
    }
    const float* in;
    __bf16* out;
    int R = 1024, C, tb;
    if (bid < 4864) { in = qkv_w; out = qwt; C = 3072; tb = bid - 4096; }
    else            { in = out_w; out = owt; C = 1024; tb = bid - 4864; }
    int ntc = C >> 6;
    int tr = tb / ntc, tc = tb % ntc;
    int r0 = tr * 64, c0 = tc * 64;
    for (int e = threadIdx.x; e < 4096; e += 256) {
        int r = e >> 6, c = e & 63;
        t[r][c] = (__bf16)in[(size_t)(r0 + r) * C + c0 + c];
    }
    __syncthreads();
    for (int e = threadIdx.x; e < 4096; e += 256) {
        int r = e >> 6, c = e & 63;
        out[(size_t)(c0 + r) * R + r0 + c] = t[c][r];
    }
}

// =============== 256x256 8-phase GEMM: C[M,N] = A[M,K] @ Bt[N,K]^T ===========
// One barrier per phase + 1-phase register-lookahead ds_reads (reads issued
// in phase p are waited at p+1 start -> complete under p's MFMAs).
// __launch_bounds__(512,1): LDS (128KiB) already caps at 1 block/CU, so let
// the allocator use up to 256 VGPR for the lookahead live ranges (round-5's
// (512,2) capped at 128 and spilled ~200MB to scratch).
// Stage safety: each staged region's reads were ISSUED >=2 phases earlier and
// completed behind an intervening LGKM0+barrier. Publishes: VMC4+BARRIER at
// ph2 (buf1 K-tile complete) and ph6 (buf0 T+2 complete); FIFO vmcnt retire.
#define BARRIER() __builtin_amdgcn_s_barrier()
#define LGKM0()                                                     \
    do {                                                            \
        asm volatile("s_waitcnt lgkmcnt(0)" ::: "memory");          \
        __builtin_amdgcn_sched_barrier(0);                          \
    } while (0)
#define VMC4() asm volatile("s_waitcnt vmcnt(4)" ::: "memory")
#define VMC6() asm volatile("s_waitcnt vmcnt(6)" ::: "memory")
#define VMC0() asm volatile("s_waitcnt vmcnt(0)" ::: "memory")

// stage A half (mh=0/1): rows {mh*64 + wid*8} and {128 + mh*64 + wid*8}
#define ST_A(buf, mh, kt)                                                     \
    do {                                                                      \
        int r0_ = (mh) * 64 + wid * 8;                                        \
        int r1_ = 128 + (mh) * 64 + wid * 8;                                  \
        gload16(Ab + (size_t)(r0_ + srow) * K + (kt) + sslot * 8,             \
                &lds[buf][0][r0_][0]);                                        \
        gload16(Ab + (size_t)(r1_ + srow) * K + (kt) + sslot * 8,             \
                &lds[buf][0][r1_][0]);                                        \
    } while (0)

// stage B half (nh=0/1)
#define ST_B(buf, nh, kt)                                                     \
    do {                                                                      \
        int r0_ = (wid >> 2) * 64 + (nh) * 32 + (wid & 3) * 8;                \
        int r1_ = r0_ + 128;                                                  \
        gload16(Bb + (size_t)(r0_ + srow) * K + (kt) + sslot * 8,             \
                &lds[buf][1][r0_][0]);                                        \
        gload16(Bb + (size_t)(r1_ + srow) * K + (kt) + sslot * 8,             \
                &lds[buf][1][r1_][0]);                                        \
    } while (0)

#define RD_A(buf, mh)                                                         \
    _Pragma("unroll") for (int mq = 0; mq < 4; ++mq)                          \
    _Pragma("unroll") for (int kk = 0; kk < 2; ++kk)                          \
        af[(mh) * 4 + mq][kk] = *(const bf16x8*)(                             \
            &lds[buf][0][wm * 128 + ((mh) * 4 + mq) * 16 + lrow]              \
                [(((kk << 2) + hi) ^ (lrow & 7)) * 8]);

#define RD_B(buf, nh)                                                         \
    _Pragma("unroll") for (int nq = 0; nq < 2; ++nq)                          \
    _Pragma("unroll") for (int kk = 0; kk < 2; ++kk)                          \
        bfr[(nh) * 2 + nq][kk] = *(const bf16x8*)(                            \
            &lds[buf][1][wn * 64 + ((nh) * 2 + nq) * 16 + lrow]               \
                [(((kk << 2) + hi) ^ (lrow & 7)) * 8]);

#define QUAD(mh, nh)                                                          \
    do {                                                                      \
        __builtin_amdgcn_s_setprio(1);                                        \
        _Pragma("unroll") for (int mq = 0; mq < 4; ++mq)                      \
        _Pragma("unroll") for (int nq = 0; nq < 2; ++nq)                      \
        _Pragma("unroll") for (int kk = 0; kk < 2; ++kk)                      \
            acc[(mh) * 4 + mq][(nh) * 2 + nq] =                               \
                MFMA16(af[(mh) * 4 + mq][kk], bfr[(nh) * 2 + nq][kk],         \
                       acc[(mh) * 4 + mq][(nh) * 2 + nq]);                    \
        __builtin_amdgcn_s_setprio(0);                                        \
    } while (0)

template <int OUTF32>
__global__ __launch_bounds__(512, 1) void gemm256(const __bf16* __restrict__ A,
                                                  const __bf16* __restrict__ Bt,
                                                  __bf16* __restrict__ Cb,
                                                  float* __restrict__ Cf,
                                                  const float* __restrict__ bias,
                                                  int M, int N, int K) {
    __shared__ __align__(16) __bf16 lds[2][2][256][64];
    const int tid = threadIdx.x;
    const int wid = tid >> 6, lane = tid & 63;
    const int lrow = lane & 15, hi = lane >> 4;
    const int wm = wid >> 2, wn = wid & 3;

    const int ntn = N >> 8;
    const int nwg = gridDim.x, bid = blockIdx.x;
    const int swz = (bid & 7) * (nwg >> 3) + (bid >> 3);
    const int tm = swz / ntn, tn = swz % ntn;

    const __bf16* Ab = A + (size_t)tm * 256 * K;
    const __bf16* Bb = Bt + (size_t)tn * 256 * K;
    const int srow = lane >> 3;              // row-within-8 for staging
    const int sslot = (lane & 7) ^ srow;     // inverse-swizzled 16B k-slot

    f32x4 acc[8][4];
#pragma unroll
    for (int m = 0; m < 8; ++m)
#pragma unroll
        for (int n = 0; n < 4; ++n) acc[m][n] = 0;

    bf16x8 af[8][2], bfr[4][2];

    // prologue: tile0 -> buf0 (8 loads); tile1 AX,AY,BX -> buf1 (6 loads)
    ST_A(0, 0, 0); ST_A(0, 1, 0); ST_B(0, 0, 0); ST_B(0, 1, 0);
    ST_A(1, 0, 64); ST_A(1, 1, 64); ST_B(1, 0, 64);
    VMC6();        // tile0's 8 loads landed
    BARRIER();     // publish buf0
    RD_A(0, 0); RD_B(0, 0);   // af0,bf0 for first quad (waited at ph0)

    const int niter = K >> 7;   // 2 K-tiles per iteration
    for (int it = 0; it < niter; ++it) {
        const int kt1 = it * 128 + 64;                          // b1 tile
        int ka = it * 128 + 128; if (ka >= K) ka = K - 64;      // b0 T+2
        int kb = it * 128 + 192; if (kb >= K) kb = K - 64;      // b1 T+3
        const bool lastit = (it == niter - 1);

        // ph0: Q00(b0) | rd af1(b0) | st BY(b1)
        LGKM0(); RD_A(0, 1); ST_B(1, 1, kt1); QUAD(0, 0); BARRIER();
        // ph1: Q10(b0) | rd bf1(b0) | st AX(b0,T+2)
        LGKM0(); RD_B(0, 1); ST_A(0, 0, ka); QUAD(1, 0); BARRIER();
        // ph2: Q01(b0) | st AY(b0,T+2) | vmc4 -> b1 complete, publish
        LGKM0(); ST_A(0, 1, ka); QUAD(0, 1); VMC4(); BARRIER();
        // ph3: Q11(b0) | rd af0,bf0(b1) | st BX(b0,T+2)
        LGKM0(); RD_A(1, 0); RD_B(1, 0); ST_B(0, 0, ka); QUAD(1, 1); BARRIER();
        // ph4: Q00(b1) | rd af1(b1) | st BY(b0,T+2)
        LGKM0(); RD_A(1, 1); ST_B(0, 1, ka); QUAD(0, 0); BARRIER();
        // ph5: Q10(b1) | rd bf1(b1) | st AX(b1,T+3)
        LGKM0(); RD_B(1, 1); ST_A(1, 0, kb); QUAD(1, 0); BARRIER();
        // ph6: Q01(b1) | st AY(b1,T+3) | vmc4 -> b0 T+2 complete, publish
        LGKM0(); ST_A(1, 1, kb); QUAD(0, 1); VMC4(); BARRIER();
        // ph7: Q11(b1) | rd af0,bf0(b0,T+2) unless last | st BX(b1,T+3)
        LGKM0();
        if (!lastit) { RD_A(0, 0); RD_B(0, 0); }
        ST_B(1, 0, kb); QUAD(1, 1); BARRIER();
    }

    VMC0();        // drain DMA before LDS goes out of scope

#pragma unroll
    for (int m = 0; m < 8; ++m)
#pragma unroll
        for (int n = 0; n < 4; ++n) {
            int row = tm * 256 + wm * 128 + m * 16 + hi * 4;
            int col = tn * 256 + wn * 64 + n * 16 + lrow;
#pragma unroll
            for (int r = 0; r < 4; ++r) {
                if constexpr (OUTF32)
                    Cf[(size_t)(row + r) * N + col] = acc[m][n][r] + bias[col];
                else
                    Cb[(size_t)(row + r) * N + col] = (__bf16)acc[m][n][r];
            }
        }
}

// ------------- fused masked attention v2, one block per (b, h) -------------
// Q and K fragments load DIRECTLY global->reg; only V LDS-staged (transposed)
// + per-wave Ps. One barrier total.
__global__ __launch_bounds__(256) void attn_kernel(const __bf16* __restrict__ qkv,
                                                   __bf16* __restrict__ aout) {
    constexpr int LDK = 72;
    __shared__ __bf16 VT[64 * LDK];   // [d][n]
    __shared__ __bf16 Ps[64 * LDK];   // [i][j], rows wr..wr+15 owned per wave

    const int b = blockIdx.x >> 4, h = blockIdx.x & 15;
    const int tid = threadIdx.x;
    const __bf16* base = qkv + (size_t)b * 60 * 3072 + h * 64;

    // zero VT pad cols n=60..63 (the only garbage that reaches arithmetic)
    VT[(tid >> 2) * LDK + 60 + (tid & 3)] = (__bf16)0.f;

    // stage V transposed: VT[d][n]
    for (int c = tid; c < 480; c += 256) {
        int n = c >> 3, d0 = (c & 7) * 8;
        bf16x8 v = *(const bf16x8*)(base + 2048 + (size_t)n * 3072 + d0);
#pragma unroll
        for (int j = 0; j < 8; ++j) VT[(d0 + j) * LDK + n] = v[j];
    }

    const int wid = tid >> 6, lane = tid & 63;
    const int lrow = lane & 15, hi = lane >> 4;
    const int wr = wid * 16;

    // Q A-frags direct from global
    bf16x8 aq[2];
#pragma unroll
    for (int kk = 0; kk < 2; ++kk)
        aq[kk] = *(const bf16x8*)(base + (size_t)(wr + lrow) * 3072 + kk * 32 + hi * 8);

    // S = Q @ K^T; K B-frags direct from global
    f32x4 s[4];
#pragma unroll
    for (int fi = 0; fi < 4; ++fi) s[fi] = 0;
#pragma unroll
    for (int kk = 0; kk < 2; ++kk)
#pragma unroll
        for (int fi = 0; fi < 4; ++fi) {
            bf16x8 bk = *(const bf16x8*)(base + 1024 +
                                         (size_t)(fi * 16 + lrow) * 3072 +
                                         kk * 32 + hi * 8);
            s[fi] = MFMA16(aq[kk], bk, s[fi]);
        }

    // masked softmax, rows i = wr + hi*4 + r, cols j = fi*16 + lrow
    const float scale = 0.125f;
#pragma unroll
    for (int r = 0; r < 4; ++r) {
        int i = wr + hi * 4 + r;
        float p[4];
        float mx = -3.0e38f;
#pragma unroll
        for (int fi = 0; fi < 4; ++fi) {
            int j = fi * 16 + lrow;
            float v = mask_ij(i, j) ? s[fi][r] * scale : -1.0e30f;
            p[fi] = v;
            mx = fmaxf(mx, v);
        }
#pragma unroll
        for (int off = 1; off <= 8; off <<= 1) mx = fmaxf(mx, __shfl_xor(mx, off));
        float se = 0.f;
#pragma unroll
        for (int fi = 0; fi < 4; ++fi) {
            p[fi] = __expf(p[fi] - mx);
            se += p[fi];
        }
#pragma unroll
        for (int off = 1; off <= 8; off <<= 1) se += __shfl_xor(se, off);
        float inv = 1.0f / se;
#pragma unroll
        for (int fi = 0; fi < 4; ++fi)
            Ps[i * LDK + fi * 16 + lrow] = (__bf16)(p[fi] * inv);
    }

    __syncthreads();   // VT staged (overlapped with QK^T + softmax)

    // O = P @ V
    f32x4 o[4];
#pragma unroll
    for (int fd = 0; fd < 4; ++fd) o[fd] = 0;
#pragma unroll
    for (int kk = 0; kk < 2; ++kk) {
        bf16x8 ap = *(const bf16x8*)(Ps + (wr + lrow) * LDK + kk * 32 + hi * 8);
#pragma unroll
        for (int fd = 0; fd < 4; ++fd) {
            bf16x8 bv = *(const bf16x8*)(VT + (fd * 16 + lrow) * LDK + kk * 32 + hi * 8);
            o[fd] = MFMA16(ap, bv, o[fd]);
        }
    }

#pragma unroll
    for (int fd = 0; fd < 4; ++fd)
#pragma unroll
        for (int r = 0; r < 4; ++r) {
            int i = wr + hi * 4 + r;
            if (i < 60)
                aout[(size_t)(b * 60 + i) * 1024 + h * 64 + fd * 16 + lrow] =
                    (__bf16)o[fd][r];
        }
}

extern "C" void kernel_launch(void* const* d_in, const int* in_sizes, int n_in,
                              void* d_out, int out_size, void* d_ws, size_t ws_size,
                              hipStream_t stream) {
    const float* x = (const float*)d_in[0];
    const float* qkv_w = (const float*)d_in[5];
    const float* out_w = (const float*)d_in[6];
    const float* out_b = (const float*)d_in[7];
    float* out = (float*)d_out;

    char* w = (char*)d_ws;
    __bf16* xb   = (__bf16*)w;                      // 30720*1024*2   = 62,914,560
    __bf16* qwt  = (__bf16*)(w + 62914560);         // 3072*1024*2    =  6,291,456
    __bf16* owt  = (__bf16*)(w + 69206016);         // 1024*1024*2    =  2,097,152
    __bf16* qkv  = (__bf16*)(w + 71303168);         // 30720*3072*2   = 188,743,680
    __bf16* aout = (__bf16*)(w + 260046848);        // 30720*1024*2   = 62,914,560

    // fused prep: cast x + transpose both weight matrices
    prep<<<dim3(5120), dim3(256), 0, stream>>>(x, xb, qkv_w, qwt, out_w, owt);

    // qkv = xb @ qkv_w : M=30720, N=3072, K=1024 -> 120x12 = 1440 blocks
    gemm256<0><<<dim3(1440), dim3(512), 0, stream>>>(xb, qwt, qkv, nullptr,
                                                     nullptr, 30720, 3072, 1024);
    // attention: one block per (b, h)
    attn_kernel<<<dim3(512 * 16), dim3(256), 0, stream>>>(qkv, aout);

    // out = aout @ out_w + out_b : M=30720, N=1024, K=1024 -> 120x4 = 480 blocks
    gemm256<1><<<dim3(480), dim3(512), 0, stream>>>(aout, owt, nullptr, out,
                                                    out_b, 30720, 1024, 1024);
}

// Round 9
// 465.819 us; speedup vs baseline: 1.2806x; 1.2806x over previous
//
#include <hip/hip_runtime.h>

typedef __bf16 bf16x8 __attribute__((ext_vector_type(8)));
typedef float f32x4 __attribute__((ext_vector_type(4)));

#define MFMA16(a, b, c) __builtin_amdgcn_mfma_f32_16x16x32_bf16(a, b, c, 0, 0, 0)

// async global->LDS, 16B per lane. LDS dest is wave-uniform base; HW writes
// base + lane*16.
__device__ __forceinline__ void gload16(const __bf16* g, __bf16* l) {
    __builtin_amdgcn_global_load_lds(
        (const __attribute__((address_space(1))) void*)g,
        (__attribute__((address_space(3))) void*)l, 16, 0, 0);
}

// channel (1..53) -> region id (0..6); index 0 unused
__constant__ signed char CREG[54] = {
    -1,
    0, 2, 2, 0, 2, 4, 2, 2, 6, 0,   // c=1..10
    4, 5, 2, 4, 6, 6, 4, 4, 6, 4,   // c=11..20
    6, 6, 6, 5, 4, 5, 6, 6, 6, 6,   // c=21..30
    4, 4, 6, 4, 6, 6, 6, 5, 4, 1,   // c=31..40
    6, 4, 6, 3, 4, 3, 1, 6, 3, 3,   // c=41..50
    3, 1, 3                          // c=51..53
};

__device__ __forceinline__ bool mask_ij(int i, int j) {
    if (i >= 60) return j == 0;     // pad rows: keep softmax finite
    if (j >= 60) return false;      // pad cols masked out
    bool ri = i < 7, rj = j < 7;
    if (ri == rj) return true;      // region-region and channel-channel all true
    if (ri) return CREG[j - 6] == i;
    return CREG[i - 6] == j;
}

// ---------------- fused prep: cast x + transpose both weights ----------------
// blocks [0,4096): cast x f32->bf16 (8 elems/thread, grid-stride)
// blocks [4096,4864): transpose+cast qkv_w [1024][3072] -> qwt [3072][1024]
// blocks [4864,5120): transpose+cast out_w [1024][1024] -> owt [1024][1024]
__global__ __launch_bounds__(256) void prep(const float* __restrict__ x,
                                            __bf16* __restrict__ xb,
                                            const float* __restrict__ qkv_w,
                                            __bf16* __restrict__ qwt,
                                            const float* __restrict__ out_w,
                                            __bf16* __restrict__ owt) {
    __shared__ __bf16 t[64][65];
    const int bid = blockIdx.x;
    if (bid < 4096) {
        const int n8 = 31457280 / 8;
        int idx = bid * 256 + threadIdx.x;
        for (int i = idx; i < n8; i += 4096 * 256) {
            f32x4 a = *(const f32x4*)(x + (size_t)i * 8);
            f32x4 b = *(const f32x4*)(x + (size_t)i * 8 + 4);
            bf16x8 v;
            v[0] = (__bf16)a[0]; v[1] = (__bf16)a[1]; v[2] = (__bf16)a[2]; v[3] = (__bf16)a[3];
            v[4] = (__bf16)b[0]; v[5] = (__bf16)b[1]; v[6] = (__bf16)b[2]; v[7] = (__bf16)b[3];
            *(bf16x8*)(xb + (size_t)i * 8) = v;
        }
        return;
    }
    const float* in;
    __bf16* out;
    int R = 1024, C, tb;
    if (bid < 4864) { in = qkv_w; out = qwt; C = 3072; tb = bid - 4096; }
    else            { in = out_w; out = owt; C = 1024; tb = bid - 4864; }
    int ntc = C >> 6;
    int tr = tb / ntc, tc = tb % ntc;
    int r0 = tr * 64, c0 = tc * 64;
    for (int e = threadIdx.x; e < 4096; e += 256) {
        int r = e >> 6, c = e & 63;
        t[r][c] = (__bf16)in[(size_t)(r0 + r) * C + c0 + c];
    }
    __syncthreads();
    for (int e = threadIdx.x; e < 4096; e += 256) {
        int r = e >> 6, c = e & 63;
        out[(size_t)(c0 + r) * R + r0 + c] = t[c][r];
    }
}

// =============== 256x256 8-phase GEMM: C[M,N] = A[M,K] @ Bt[N,K]^T ===========
// Round-4 VALIDATED schedule (205us QKV, MfmaUtil 41%, 0 conflicts):
// 2 barriers/phase, in-phase ds_reads (short live ranges -> no spill at the
// compiler's 128-VGPR allocation; one-barrier lookahead variants spill, R5/R8).
// Change vs R4: last iteration skips all T+2/T+3 prefetches (were junk clamped
// loads); ph3 uses VMC0 on lastit (drains exactly the 8 outstanding b1 loads:
// 6 from prev ph5/6/7 + 2 from ph0); ph7 needs no wait; epilogue drain free.
#define BARRIER() __builtin_amdgcn_s_barrier()
#define LGKM0()                                                     \
    do {                                                            \
        asm volatile("s_waitcnt lgkmcnt(0)" ::: "memory");          \
        __builtin_amdgcn_sched_barrier(0);                          \
    } while (0)
#define VMC6() asm volatile("s_waitcnt vmcnt(6)" ::: "memory")
#define VMC0() asm volatile("s_waitcnt vmcnt(0)" ::: "memory")

// stage A half (mh=0/1): rows {mh*64 + wid*8} and {128 + mh*64 + wid*8}
#define ST_A(buf, mh, kt)                                                     \
    do {                                                                      \
        int r0_ = (mh) * 64 + wid * 8;                                        \
        int r1_ = 128 + (mh) * 64 + wid * 8;                                  \
        gload16(Ab + (size_t)(r0_ + srow) * K + (kt) + sslot * 8,             \
                &lds[buf][0][r0_][0]);                                        \
        gload16(Ab + (size_t)(r1_ + srow) * K + (kt) + sslot * 8,             \
                &lds[buf][0][r1_][0]);                                        \
    } while (0)

// stage B half (nh=0/1)
#define ST_B(buf, nh, kt)                                                     \
    do {                                                                      \
        int r0_ = (wid >> 2) * 64 + (nh) * 32 + (wid & 3) * 8;                \
        int r1_ = r0_ + 128;                                                  \
        gload16(Bb + (size_t)(r0_ + srow) * K + (kt) + sslot * 8,             \
                &lds[buf][1][r0_][0]);                                        \
        gload16(Bb + (size_t)(r1_ + srow) * K + (kt) + sslot * 8,             \
                &lds[buf][1][r1_][0]);                                        \
    } while (0)

#define RD_A(buf, mh)                                                         \
    _Pragma("unroll") for (int mq = 0; mq < 4; ++mq)                          \
    _Pragma("unroll") for (int kk = 0; kk < 2; ++kk)                          \
        af[(mh) * 4 + mq][kk] = *(const bf16x8*)(                             \
            &lds[buf][0][wm * 128 + ((mh) * 4 + mq) * 16 + lrow]              \
                [(((kk << 2) + hi) ^ (lrow & 7)) * 8]);

#define RD_B(buf, nh)                                                         \
    _Pragma("unroll") for (int nq = 0; nq < 2; ++nq)                          \
    _Pragma("unroll") for (int kk = 0; kk < 2; ++kk)                          \
        bfr[(nh) * 2 + nq][kk] = *(const bf16x8*)(                            \
            &lds[buf][1][wn * 64 + ((nh) * 2 + nq) * 16 + lrow]               \
                [(((kk << 2) + hi) ^ (lrow & 7)) * 8]);

#define QUAD(mh, nh)                                                          \
    do {                                                                      \
        __builtin_amdgcn_s_setprio(1);                                        \
        _Pragma("unroll") for (int mq = 0; mq < 4; ++mq)                      \
        _Pragma("unroll") for (int nq = 0; nq < 2; ++nq)                      \
        _Pragma("unroll") for (int kk = 0; kk < 2; ++kk)                      \
            acc[(mh) * 4 + mq][(nh) * 2 + nq] =                               \
                MFMA16(af[(mh) * 4 + mq][kk], bfr[(nh) * 2 + nq][kk],         \
                       acc[(mh) * 4 + mq][(nh) * 2 + nq]);                    \
        __builtin_amdgcn_s_setprio(0);                                        \
    } while (0)

template <int OUTF32>
__global__ __launch_bounds__(512, 2) void gemm256(const __bf16* __restrict__ A,
                                                  const __bf16* __restrict__ Bt,
                                                  __bf16* __restrict__ Cb,
                                                  float* __restrict__ Cf,
                                                  const float* __restrict__ bias,
                                                  int M, int N, int K) {
    __shared__ __align__(16) __bf16 lds[2][2][256][64];
    const int tid = threadIdx.x;
    const int wid = tid >> 6, lane = tid & 63;
    const int lrow = lane & 15, hi = lane >> 4;
    const int wm = wid >> 2, wn = wid & 3;

    const int ntn = N >> 8;
    const int nwg = gridDim.x, bid = blockIdx.x;
    const int swz = (bid & 7) * (nwg >> 3) + (bid >> 3);
    const int tm = swz / ntn, tn = swz % ntn;

    const __bf16* Ab = A + (size_t)tm * 256 * K;
    const __bf16* Bb = Bt + (size_t)tn * 256 * K;
    const int srow = lane >> 3;              // row-within-8 for staging
    const int sslot = (lane & 7) ^ srow;     // inverse-swizzled 16B k-slot

    f32x4 acc[8][4];
#pragma unroll
    for (int m = 0; m < 8; ++m)
#pragma unroll
        for (int n = 0; n < 4; ++n) acc[m][n] = 0;

    bf16x8 af[8][2], bfr[4][2];

    // prologue: tile0 complete into buf0; tile1 AX,AY,BX into buf1 (14 loads)
    ST_A(0, 0, 0); ST_A(0, 1, 0); ST_B(0, 0, 0); ST_B(0, 1, 0);
    ST_A(1, 0, 64); ST_A(1, 1, 64); ST_B(1, 0, 64);
    VMC6();        // oldest 8 (= tile0) landed
    BARRIER();     // publish to all waves

    const int niter = K >> 7;   // 2 K-tiles per iteration
    for (int it = 0; it < niter; ++it) {
        const int kt1 = it * 128 + 64;       // b1 K-tile (always staged)
        const int ka = it * 128 + 128;       // b0 T+2 src (only if !lastit)
        const int kb = it * 128 + 192;       // b1 T+3 src (only if !lastit)
        const bool lastit = (it == niter - 1);

        // ph0: T0 quad(0,0) from buf0; stage BY(b1)
        RD_A(0, 0); RD_B(0, 0);
        ST_B(1, 1, kt1);
        BARRIER(); LGKM0(); QUAD(0, 0); BARRIER();
        // ph1: quad(1,0); stage AX(T+2)
        RD_A(0, 1);
        if (!lastit) ST_A(0, 0, ka);
        BARRIER(); LGKM0(); QUAD(1, 0); BARRIER();
        // ph2: quad(0,1); stage AY(T+2)
        RD_B(0, 1);
        if (!lastit) ST_A(0, 1, ka);
        BARRIER(); LGKM0(); QUAD(0, 1); BARRIER();
        // ph3: quad(1,1); stage BX(T+2); publish b1
        if (!lastit) { ST_B(0, 0, ka); VMC6(); } else { VMC0(); }
        BARRIER(); LGKM0(); QUAD(1, 1); BARRIER();
        // ph4: T1 quad(0,0) from buf1; stage BY(T+2)
        RD_A(1, 0); RD_B(1, 0);
        if (!lastit) ST_B(0, 1, ka);
        BARRIER(); LGKM0(); QUAD(0, 0); BARRIER();
        // ph5: quad(1,0); stage AX(T+3)
        RD_A(1, 1);
        if (!lastit) ST_A(1, 0, kb);
        BARRIER(); LGKM0(); QUAD(1, 0); BARRIER();
        // ph6: quad(0,1); stage AY(T+3)
        RD_B(1, 1);
        if (!lastit) ST_A(1, 1, kb);
        BARRIER(); LGKM0(); QUAD(0, 1); BARRIER();
        // ph7: quad(1,1); stage BX(T+3); publish T+2's buf0
        if (!lastit) { ST_B(1, 0, kb); VMC6(); }
        BARRIER(); LGKM0(); QUAD(1, 1); BARRIER();
    }

    VMC0();   // free: nothing outstanding after lastit

#pragma unroll
    for (int m = 0; m < 8; ++m)
#pragma unroll
        for (int n = 0; n < 4; ++n) {
            int row = tm * 256 + wm * 128 + m * 16 + hi * 4;
            int col = tn * 256 + wn * 64 + n * 16 + lrow;
#pragma unroll
            for (int r = 0; r < 4; ++r) {
                if constexpr (OUTF32)
                    Cf[(size_t)(row + r) * N + col] = acc[m][n][r] + bias[col];
                else
                    Cb[(size_t)(row + r) * N + col] = (__bf16)acc[m][n][r];
            }
        }
}

// ------------- fused masked attention v2, one block per (b, h) -------------
// Q and K fragments load DIRECTLY global->reg; only V LDS-staged (transposed)
// + per-wave Ps. One barrier total.
__global__ __launch_bounds__(256) void attn_kernel(const __bf16* __restrict__ qkv,
                                                   __bf16* __restrict__ aout) {
    constexpr int LDK = 72;
    __shared__ __bf16 VT[64 * LDK];   // [d][n]
    __shared__ __bf16 Ps[64 * LDK];   // [i][j], rows wr..wr+15 owned per wave

    const int b = blockIdx.x >> 4, h = blockIdx.x & 15;
    const int tid = threadIdx.x;
    const __bf16* base = qkv + (size_t)b * 60 * 3072 + h * 64;

    // zero VT pad cols n=60..63 (the only garbage that reaches arithmetic)
    VT[(tid >> 2) * LDK + 60 + (tid & 3)] = (__bf16)0.f;

    // stage V transposed: VT[d][n]
    for (int c = tid; c < 480; c += 256) {
        int n = c >> 3, d0 = (c & 7) * 8;
        bf16x8 v = *(const bf16x8*)(base + 2048 + (size_t)n * 3072 + d0);
#pragma unroll
        for (int j = 0; j < 8; ++j) VT[(d0 + j) * LDK + n] = v[j];
    }

    const int wid = tid >> 6, lane = tid & 63;
    const int lrow = lane & 15, hi = lane >> 4;
    const int wr = wid * 16;

    // Q A-frags direct from global
    bf16x8 aq[2];
#pragma unroll
    for (int kk = 0; kk < 2; ++kk)
        aq[kk] = *(const bf16x8*)(base + (size_t)(wr + lrow) * 3072 + kk * 32 + hi * 8);

    // S = Q @ K^T; K B-frags direct from global
    f32x4 s[4];
#pragma unroll
    for (int fi = 0; fi < 4; ++fi) s[fi] = 0;
#pragma unroll
    for (int kk = 0; kk < 2; ++kk)
#pragma unroll
        for (int fi = 0; fi < 4; ++fi) {
            bf16x8 bk = *(const bf16x8*)(base + 1024 +
                                         (size_t)(fi * 16 + lrow) * 3072 +
                                         kk * 32 + hi * 8);
            s[fi] = MFMA16(aq[kk], bk, s[fi]);
        }

    // masked softmax, rows i = wr + hi*4 + r, cols j = fi*16 + lrow
    const float scale = 0.125f;
#pragma unroll
    for (int r = 0; r < 4; ++r) {
        int i = wr + hi * 4 + r;
        float p[4];
        float mx = -3.0e38f;
#pragma unroll
        for (int fi = 0; fi < 4; ++fi) {
            int j = fi * 16 + lrow;
            float v = mask_ij(i, j) ? s[fi][r] * scale : -1.0e30f;
            p[fi] = v;
            mx = fmaxf(mx, v);
        }
#pragma unroll
        for (int off = 1; off <= 8; off <<= 1) mx = fmaxf(mx, __shfl_xor(mx, off));
        float se = 0.f;
#pragma unroll
        for (int fi = 0; fi < 4; ++fi) {
            p[fi] = __expf(p[fi] - mx);
            se += p[fi];
        }
#pragma unroll
        for (int off = 1; off <= 8; off <<= 1) se += __shfl_xor(se, off);
        float inv = 1.0f / se;
#pragma unroll
        for (int fi = 0; fi < 4; ++fi)
            Ps[i * LDK + fi * 16 + lrow] = (__bf16)(p[fi] * inv);
    }

    __syncthreads();   // VT staged (overlapped with QK^T + softmax)

    // O = P @ V
    f32x4 o[4];
#pragma unroll
    for (int fd = 0; fd < 4; ++fd) o[fd] = 0;
#pragma unroll
    for (int kk = 0; kk < 2; ++kk) {
        bf16x8 ap = *(const bf16x8*)(Ps + (wr + lrow) * LDK + kk * 32 + hi * 8);
#pragma unroll
        for (int fd = 0; fd < 4; ++fd) {
            bf16x8 bv = *(const bf16x8*)(VT + (fd * 16 + lrow) * LDK + kk * 32 + hi * 8);
            o[fd] = MFMA16(ap, bv, o[fd]);
        }
    }

#pragma unroll
    for (int fd = 0; fd < 4; ++fd)
#pragma unroll
        for (int r = 0; r < 4; ++r) {
            int i = wr + hi * 4 + r;
            if (i < 60)
                aout[(size_t)(b * 60 + i) * 1024 + h * 64 + fd * 16 + lrow] =
                    (__bf16)o[fd][r];
        }
}

extern "C" void kernel_launch(void* const* d_in, const int* in_sizes, int n_in,
                              void* d_out, int out_size, void* d_ws, size_t ws_size,
                              hipStream_t stream) {
    const float* x = (const float*)d_in[0];
    const float* qkv_w = (const float*)d_in[5];
    const float* out_w = (const float*)d_in[6];
    const float* out_b = (const float*)d_in[7];
    float* out = (float*)d_out;

    char* w = (char*)d_ws;
    __bf16* xb   = (__bf16*)w;                      // 30720*1024*2   = 62,914,560
    __bf16* qwt  = (__bf16*)(w + 62914560);         // 3072*1024*2    =  6,291,456
    __bf16* owt  = (__bf16*)(w + 69206016);         // 1024*1024*2    =  2,097,152
    __bf16* qkv  = (__bf16*)(w + 71303168);         // 30720*3072*2   = 188,743,680
    __bf16* aout = (__bf16*)(w + 260046848);        // 30720*1024*2   = 62,914,560

    // fused prep: cast x + transpose both weight matrices
    prep<<<dim3(5120), dim3(256), 0, stream>>>(x, xb, qkv_w, qwt, out_w, owt);

    // qkv = xb @ qkv_w : M=30720, N=3072, K=1024 -> 120x12 = 1440 blocks
    gemm256<0><<<dim3(1440), dim3(512), 0, stream>>>(xb, qwt, qkv, nullptr,
                                                     nullptr, 30720, 3072, 1024);
    // attention: one block per (b, h)
    attn_kernel<<<dim3(512 * 16), dim3(256), 0, stream>>>(qkv, aout);

    // out = aout @ out_w + out_b : M=30720, N=1024, K=1024 -> 120x4 = 480 blocks
    gemm256<1><<<dim3(480), dim3(512), 0, stream>>>(aout, owt, nullptr, out,
                                                    out_b, 30720, 1024, 1024);
}

// Round 10
// 425.104 us; speedup vs baseline: 1.4033x; 1.0958x over previous
//
#include <hip/hip_runtime.h>

typedef __bf16 bf16x8 __attribute__((ext_vector_type(8)));
typedef float f32x4 __attribute__((ext_vector_type(4)));

#define MFMA16(a, b, c) __builtin_amdgcn_mfma_f32_16x16x32_bf16(a, b, c, 0, 0, 0)

// async global->LDS, 16B per lane. LDS dest is wave-uniform base; HW writes
// base + lane*16.
__device__ __forceinline__ void gload16(const __bf16* g, __bf16* l) {
    __builtin_amdgcn_global_load_lds(
        (const __attribute__((address_space(1))) void*)g,
        (__attribute__((address_space(3))) void*)l, 16, 0, 0);
}

// channel (1..53) -> region id (0..6); index 0 unused
__constant__ signed char CREG[54] = {
    -1,
    0, 2, 2, 0, 2, 4, 2, 2, 6, 0,   // c=1..10
    4, 5, 2, 4, 6, 6, 4, 4, 6, 4,   // c=11..20
    6, 6, 6, 5, 4, 5, 6, 6, 6, 6,   // c=21..30
    4, 4, 6, 4, 6, 6, 6, 5, 4, 1,   // c=31..40
    6, 4, 6, 3, 4, 3, 1, 6, 3, 3,   // c=41..50
    3, 1, 3                          // c=51..53
};

__device__ __forceinline__ bool mask_ij(int i, int j) {
    if (i >= 60) return j == 0;     // pad rows: keep softmax finite
    if (j >= 60) return false;      // pad cols masked out
    bool ri = i < 7, rj = j < 7;
    if (ri == rj) return true;      // region-region and channel-channel all true
    if (ri) return CREG[j - 6] == i;
    return CREG[i - 6] == j;
}

// ---------------- fused prep: cast x + transpose both weights ----------------
__global__ __launch_bounds__(256) void prep(const float* __restrict__ x,
                                            __bf16* __restrict__ xb,
                                            const float* __restrict__ qkv_w,
                                            __bf16* __restrict__ qwt,
                                            const float* __restrict__ out_w,
                                            __bf16* __restrict__ owt) {
    __shared__ __bf16 t[64][65];
    const int bid = blockIdx.x;
    if (bid < 4096) {
        const int n8 = 31457280 / 8;
        int idx = bid * 256 + threadIdx.x;
        for (int i = idx; i < n8; i += 4096 * 256) {
            f32x4 a = *(const f32x4*)(x + (size_t)i * 8);
            f32x4 b = *(const f32x4*)(x + (size_t)i * 8 + 4);
            bf16x8 v;
            v[0] = (__bf16)a[0]; v[1] = (__bf16)a[1]; v[2] = (__bf16)a[2]; v[3] = (__bf16)a[3];
            v[4] = (__bf16)b[0]; v[5] = (__bf16)b[1]; v[6] = (__bf16)b[2]; v[7] = (__bf16)b[3];
            *(bf16x8*)(xb + (size_t)i * 8) = v;
        }
        return;
    }
    const float* in;
    __bf16* out;
    int R = 1024, C, tb;
    if (bid < 4864) { in = qkv_w; out = qwt; C = 3072; tb = bid - 4096; }
    else            { in = out_w; out = owt; C = 1024; tb = bid - 4864; }
    int ntc = C >> 6;
    int tr = tb / ntc, tc = tb % ntc;
    int r0 = tr * 64, c0 = tc * 64;
    for (int e = threadIdx.x; e < 4096; e += 256) {
        int r = e >> 6, c = e & 63;
        t[r][c] = (__bf16)in[(size_t)(r0 + r) * C + c0 + c];
    }
    __syncthreads();
    for (int e = threadIdx.x; e < 4096; e += 256) {
        int r = e >> 6, c = e & 63;
        out[(size_t)(c0 + r) * R + r0 + c] = t[c][r];
    }
}

// ============ 128x128 8-phase GEMM (2 blocks/CU): C = A @ Bt^T ===============
// R7's VALIDATED schedule shrunk to 128x128 / 4 waves / 64 KiB LDS so TWO
// independent blocks co-reside per CU: one block's LDS phases overlap the
// other's MFMA phases (the R7 256x256 config serialized them at 1 block/CU).
// Schedule semantics byte-for-byte identical: 8 phases, 2 barriers/phase,
// in-phase ds_reads (short live ranges - no spill), 2 gload16 per ST macro,
// VMC6 publishes at ph3/ph7, branch-free loop with clamped junk prefetch.
#define BARRIER() __builtin_amdgcn_s_barrier()
#define LGKM0()                                                     \
    do {                                                            \
        asm volatile("s_waitcnt lgkmcnt(0)" ::: "memory");          \
        __builtin_amdgcn_sched_barrier(0);                          \
    } while (0)
#define VMC6() asm volatile("s_waitcnt vmcnt(6)" ::: "memory")
#define VMC0() asm volatile("s_waitcnt vmcnt(0)" ::: "memory")

// stage A half (mh=0/1): each wave 2 gload16 covering 16 rows; 4 waves = 64 rows
#define ST_A(buf, mh, kt)                                                     \
    do {                                                                      \
        int r0_ = (mh) * 64 + wid * 16;                                       \
        int r1_ = r0_ + 8;                                                    \
        gload16(Ab + (size_t)(r0_ + srow) * K + (kt) + sslot * 8,             \
                &lds[buf][0][r0_][0]);                                        \
        gload16(Ab + (size_t)(r1_ + srow) * K + (kt) + sslot * 8,             \
                &lds[buf][0][r1_][0]);                                        \
    } while (0)

// stage B half (nh=0/1)
#define ST_B(buf, nh, kt)                                                     \
    do {                                                                      \
        int r0_ = (nh) * 64 + wid * 16;                                       \
        int r1_ = r0_ + 8;                                                    \
        gload16(Bb + (size_t)(r0_ + srow) * K + (kt) + sslot * 8,             \
                &lds[buf][1][r0_][0]);                                        \
        gload16(Bb + (size_t)(r1_ + srow) * K + (kt) + sslot * 8,             \
                &lds[buf][1][r1_][0]);                                        \
    } while (0)

#define RD_A(buf, mh)                                                         \
    _Pragma("unroll") for (int mq = 0; mq < 2; ++mq)                          \
    _Pragma("unroll") for (int kk = 0; kk < 2; ++kk)                          \
        af[(mh) * 2 + mq][kk] = *(const bf16x8*)(                             \
            &lds[buf][0][wm * 64 + ((mh) * 2 + mq) * 16 + lrow]               \
                [(((kk << 2) + hi) ^ (lrow & 7)) * 8]);

#define RD_B(buf, nh)                                                         \
    _Pragma("unroll") for (int nq = 0; nq < 2; ++nq)                          \
    _Pragma("unroll") for (int kk = 0; kk < 2; ++kk)                          \
        bfr[(nh) * 2 + nq][kk] = *(const bf16x8*)(                            \
            &lds[buf][1][wn * 64 + ((nh) * 2 + nq) * 16 + lrow]               \
                [(((kk << 2) + hi) ^ (lrow & 7)) * 8]);

#define QUAD(mh, nh)                                                          \
    do {                                                                      \
        __builtin_amdgcn_s_setprio(1);                                        \
        _Pragma("unroll") for (int mq = 0; mq < 2; ++mq)                      \
        _Pragma("unroll") for (int nq = 0; nq < 2; ++nq)                      \
        _Pragma("unroll") for (int kk = 0; kk < 2; ++kk)                      \
            acc[(mh) * 2 + mq][(nh) * 2 + nq] =                               \
                MFMA16(af[(mh) * 2 + mq][kk], bfr[(nh) * 2 + nq][kk],         \
                       acc[(mh) * 2 + mq][(nh) * 2 + nq]);                    \
        __builtin_amdgcn_s_setprio(0);                                        \
    } while (0)

template <int OUTF32>
__global__ __launch_bounds__(256, 2) void gemm128(const __bf16* __restrict__ A,
                                                  const __bf16* __restrict__ Bt,
                                                  __bf16* __restrict__ Cb,
                                                  float* __restrict__ Cf,
                                                  const float* __restrict__ bias,
                                                  int M, int N, int K) {
    __shared__ __align__(16) __bf16 lds[2][2][128][64];   // 64 KiB
    const int tid = threadIdx.x;
    const int wid = tid >> 6, lane = tid & 63;
    const int lrow = lane & 15, hi = lane >> 4;
    const int wm = wid >> 1, wn = wid & 1;   // 2x2 wave grid, 64x64 each

    const int ntn = N >> 7;
    const int nwg = gridDim.x, bid = blockIdx.x;
    const int swz = (bid & 7) * (nwg >> 3) + (bid >> 3);
    const int tm = swz / ntn, tn = swz % ntn;

    const __bf16* Ab = A + (size_t)tm * 128 * K;
    const __bf16* Bb = Bt + (size_t)tn * 128 * K;
    const int srow = lane >> 3;              // row-within-8 for staging
    const int sslot = (lane & 7) ^ srow;     // inverse-swizzled 16B k-slot

    f32x4 acc[4][4];
#pragma unroll
    for (int m = 0; m < 4; ++m)
#pragma unroll
        for (int n = 0; n < 4; ++n) acc[m][n] = 0;

    bf16x8 af[4][2], bfr[4][2];

    // prologue: tile0 complete into buf0; tile1 AX,AY,BX into buf1 (14 loads)
    ST_A(0, 0, 0); ST_A(0, 1, 0); ST_B(0, 0, 0); ST_B(0, 1, 0);
    ST_A(1, 0, 64); ST_A(1, 1, 64); ST_B(1, 0, 64);
    VMC6();        // oldest 8 (= tile0) landed
    BARRIER();     // publish to all waves

    const int niter = K >> 7;   // 2 K-tiles per iteration
    for (int it = 0; it < niter; ++it) {
        const int kt1 = it * 128 + 64;
        const int ka = (it * 128 + 128 < K) ? it * 128 + 128 : K - 64;  // T+2 src
        const int kb = (kt1 + 128 < K) ? kt1 + 128 : K - 64;            // T+3 src

        // ph0: T0 quad(0,0) from buf0; stage BY(b1)
        RD_A(0, 0); RD_B(0, 0);
        ST_B(1, 1, kt1);
        BARRIER(); LGKM0(); QUAD(0, 0); BARRIER();
        // ph1: quad(1,0); stage AX(T+2)
        RD_A(0, 1);
        ST_A(0, 0, ka);
        BARRIER(); LGKM0(); QUAD(1, 0); BARRIER();
        // ph2: quad(0,1); stage AY(T+2)
        RD_B(0, 1);
        ST_A(0, 1, ka);
        BARRIER(); LGKM0(); QUAD(0, 1); BARRIER();
        // ph3: quad(1,1); stage BX(T+2); vmcnt(6) -> b1 landed
        ST_B(0, 0, ka);
        VMC6();
        BARRIER(); LGKM0(); QUAD(1, 1); BARRIER();
        // ph4: T1 quad(0,0) from buf1; stage BY(T+2)
        RD_A(1, 0); RD_B(1, 0);
        ST_B(0, 1, ka);
        BARRIER(); LGKM0(); QUAD(0, 0); BARRIER();
        // ph5: quad(1,0); stage AX(T+3)
        RD_A(1, 1);
        ST_A(1, 0, kb);
        BARRIER(); LGKM0(); QUAD(1, 0); BARRIER();
        // ph6: quad(0,1); stage AY(T+3)
        RD_B(1, 1);
        ST_A(1, 1, kb);
        BARRIER(); LGKM0(); QUAD(0, 1); BARRIER();
        // ph7: quad(1,1); stage BX(T+3); vmcnt(6) -> T+2 buf0 landed
        ST_B(1, 0, kb);
        VMC6();
        BARRIER(); LGKM0(); QUAD(1, 1); BARRIER();
    }

    VMC0();        // drain DMA before LDS is released
    BARRIER();

#pragma unroll
    for (int m = 0; m < 4; ++m)
#pragma unroll
        for (int n = 0; n < 4; ++n) {
            int row = tm * 128 + wm * 64 + m * 16 + hi * 4;
            int col = tn * 128 + wn * 64 + n * 16 + lrow;
#pragma unroll
            for (int r = 0; r < 4; ++r) {
                if constexpr (OUTF32)
                    Cf[(size_t)(row + r) * N + col] = acc[m][n][r] + bias[col];
                else
                    Cb[(size_t)(row + r) * N + col] = (__bf16)acc[m][n][r];
            }
        }
}

// ------------- fused masked attention v2, one block per (b, h) -------------
__global__ __launch_bounds__(256) void attn_kernel(const __bf16* __restrict__ qkv,
                                                   __bf16* __restrict__ aout) {
    constexpr int LDK = 72;
    __shared__ __bf16 VT[64 * LDK];   // [d][n]
    __shared__ __bf16 Ps[64 * LDK];   // [i][j], rows wr..wr+15 owned per wave

    const int b = blockIdx.x >> 4, h = blockIdx.x & 15;
    const int tid = threadIdx.x;
    const __bf16* base = qkv + (size_t)b * 60 * 3072 + h * 64;

    // zero VT pad cols n=60..63 (the only garbage that reaches arithmetic)
    VT[(tid >> 2) * LDK + 60 + (tid & 3)] = (__bf16)0.f;

    // stage V transposed: VT[d][n]
    for (int c = tid; c < 480; c += 256) {
        int n = c >> 3, d0 = (c & 7) * 8;
        bf16x8 v = *(const bf16x8*)(base + 2048 + (size_t)n * 3072 + d0);
#pragma unroll
        for (int j = 0; j < 8; ++j) VT[(d0 + j) * LDK + n] = v[j];
    }

    const int wid = tid >> 6, lane = tid & 63;
    const int lrow = lane & 15, hi = lane >> 4;
    const int wr = wid * 16;

    // Q A-frags direct from global
    bf16x8 aq[2];
#pragma unroll
    for (int kk = 0; kk < 2; ++kk)
        aq[kk] = *(const bf16x8*)(base + (size_t)(wr + lrow) * 3072 + kk * 32 + hi * 8);

    // S = Q @ K^T; K B-frags direct from global
    f32x4 s[4];
#pragma unroll
    for (int fi = 0; fi < 4; ++fi) s[fi] = 0;
#pragma unroll
    for (int kk = 0; kk < 2; ++kk)
#pragma unroll
        for (int fi = 0; fi < 4; ++fi) {
            bf16x8 bk = *(const bf16x8*)(base + 1024 +
                                         (size_t)(fi * 16 + lrow) * 3072 +
                                         kk * 32 + hi * 8);
            s[fi] = MFMA16(aq[kk], bk, s[fi]);
        }

    // masked softmax, rows i = wr + hi*4 + r, cols j = fi*16 + lrow
    const float scale = 0.125f;
#pragma unroll
    for (int r = 0; r < 4; ++r) {
        int i = wr + hi * 4 + r;
        float p[4];
        float mx = -3.0e38f;
#pragma unroll
        for (int fi = 0; fi < 4; ++fi) {
            int j = fi * 16 + lrow;
            float v = mask_ij(i, j) ? s[fi][r] * scale : -1.0e30f;
            p[fi] = v;
            mx = fmaxf(mx, v);
        }
#pragma unroll
        for (int off = 1; off <= 8; off <<= 1) mx = fmaxf(mx, __shfl_xor(mx, off));
        float se = 0.f;
#pragma unroll
        for (int fi = 0; fi < 4; ++fi) {
            p[fi] = __expf(p[fi] - mx);
            se += p[fi];
        }
#pragma unroll
        for (int off = 1; off <= 8; off <<= 1) se += __shfl_xor(se, off);
        float inv = 1.0f / se;
#pragma unroll
        for (int fi = 0; fi < 4; ++fi)
            Ps[i * LDK + fi * 16 + lrow] = (__bf16)(p[fi] * inv);
    }

    __syncthreads();   // VT staged (overlapped with QK^T + softmax)

    // O = P @ V
    f32x4 o[4];
#pragma unroll
    for (int fd = 0; fd < 4; ++fd) o[fd] = 0;
#pragma unroll
    for (int kk = 0; kk < 2; ++kk) {
        bf16x8 ap = *(const bf16x8*)(Ps + (wr + lrow) * LDK + kk * 32 + hi * 8);
#pragma unroll
        for (int fd = 0; fd < 4; ++fd) {
            bf16x8 bv = *(const bf16x8*)(VT + (fd * 16 + lrow) * LDK + kk * 32 + hi * 8);
            o[fd] = MFMA16(ap, bv, o[fd]);
        }
    }

#pragma unroll
    for (int fd = 0; fd < 4; ++fd)
#pragma unroll
        for (int r = 0; r < 4; ++r) {
            int i = wr + hi * 4 + r;
            if (i < 60)
                aout[(size_t)(b * 60 + i) * 1024 + h * 64 + fd * 16 + lrow] =
                    (__bf16)o[fd][r];
        }
}

extern "C" void kernel_launch(void* const* d_in, const int* in_sizes, int n_in,
                              void* d_out, int out_size, void* d_ws, size_t ws_size,
                              hipStream_t stream) {
    const float* x = (const float*)d_in[0];
    const float* qkv_w = (const float*)d_in[5];
    const float* out_w = (const float*)d_in[6];
    const float* out_b = (const float*)d_in[7];
    float* out = (float*)d_out;

    char* w = (char*)d_ws;
    __bf16* xb   = (__bf16*)w;                      // 30720*1024*2   = 62,914,560
    __bf16* qwt  = (__bf16*)(w + 62914560);         // 3072*1024*2    =  6,291,456
    __bf16* owt  = (__bf16*)(w + 69206016);         // 1024*1024*2    =  2,097,152
    __bf16* qkv  = (__bf16*)(w + 71303168);         // 30720*3072*2   = 188,743,680
    __bf16* aout = (__bf16*)(w + 260046848);        // 30720*1024*2   = 62,914,560

    // fused prep: cast x + transpose both weight matrices
    prep<<<dim3(5120), dim3(256), 0, stream>>>(x, xb, qkv_w, qwt, out_w, owt);

    // qkv = xb @ qkv_w : M=30720, N=3072, K=1024 -> 240x24 = 5760 blocks
    gemm128<0><<<dim3(5760), dim3(256), 0, stream>>>(xb, qwt, qkv, nullptr,
                                                     nullptr, 30720, 3072, 1024);
    // attention: one block per (b, h)
    attn_kernel<<<dim3(512 * 16), dim3(256), 0, stream>>>(qkv, aout);

    // out = aout @ out_w + out_b : M=30720, N=1024, K=1024 -> 240x8 = 1920 blocks
    gemm128<1><<<dim3(1920), dim3(256), 0, stream>>>(aout, owt, nullptr, out,
                                                     out_b, 30720, 1024, 1024);
}

// Round 11
// 388.556 us; speedup vs baseline: 1.5353x; 1.0941x over previous
//
#include <hip/hip_runtime.h>

typedef __bf16 bf16x8 __attribute__((ext_vector_type(8)));
typedef float f32x4 __attribute__((ext_vector_type(4)));

#define MFMA16(a, b, c) __builtin_amdgcn_mfma_f32_16x16x32_bf16(a, b, c, 0, 0, 0)

// async global->LDS, 16B per lane. LDS dest is wave-uniform base; HW writes
// base + lane*16.
__device__ __forceinline__ void gload16(const __bf16* g, __bf16* l) {
    __builtin_amdgcn_global_load_lds(
        (const __attribute__((address_space(1))) void*)g,
        (__attribute__((address_space(3))) void*)l, 16, 0, 0);
}

// channel (1..53) -> region id (0..6); index 0 unused
__constant__ signed char CREG[54] = {
    -1,
    0, 2, 2, 0, 2, 4, 2, 2, 6, 0,   // c=1..10
    4, 5, 2, 4, 6, 6, 4, 4, 6, 4,   // c=11..20
    6, 6, 6, 5, 4, 5, 6, 6, 6, 6,   // c=21..30
    4, 4, 6, 4, 6, 6, 6, 5, 4, 1,   // c=31..40
    6, 4, 6, 3, 4, 3, 1, 6, 3, 3,   // c=41..50
    3, 1, 3                          // c=51..53
};

__device__ __forceinline__ bool mask_ij(int i, int j) {
    if (i >= 60) return j == 0;     // pad rows: keep softmax finite
    if (j >= 60) return false;      // pad cols masked out
    bool ri = i < 7, rj = j < 7;
    if (ri == rj) return true;      // region-region and channel-channel all true
    if (ri) return CREG[j - 6] == i;
    return CREG[i - 6] == j;
}

// ---------------- fused prep: cast x + transpose both weights ----------------
// blocks [0,4096): cast x f32->bf16 (8 elems/thread, grid-stride)
// blocks [4096,4864): transpose+cast qkv_w [1024][3072] -> qwt [3072][1024]
// blocks [4864,5120): transpose+cast out_w [1024][1024] -> owt [1024][1024]
__global__ __launch_bounds__(256) void prep(const float* __restrict__ x,
                                            __bf16* __restrict__ xb,
                                            const float* __restrict__ qkv_w,
                                            __bf16* __restrict__ qwt,
                                            const float* __restrict__ out_w,
                                            __bf16* __restrict__ owt) {
    __shared__ __bf16 t[64][65];
    const int bid = blockIdx.x;
    if (bid < 4096) {
        const int n8 = 31457280 / 8;
        int idx = bid * 256 + threadIdx.x;
        for (int i = idx; i < n8; i += 4096 * 256) {
            f32x4 a = *(const f32x4*)(x + (size_t)i * 8);
            f32x4 b = *(const f32x4*)(x + (size_t)i * 8 + 4);
            bf16x8 v;
            v[0] = (__bf16)a[0]; v[1] = (__bf16)a[1]; v[2] = (__bf16)a[2]; v[3] = (__bf16)a[3];
            v[4] = (__bf16)b[0]; v[5] = (__bf16)b[1]; v[6] = (__bf16)b[2]; v[7] = (__bf16)b[3];
            *(bf16x8*)(xb + (size_t)i * 8) = v;
        }
        return;
    }
    const float* in;
    __bf16* out;
    int R = 1024, C, tb;
    if (bid < 4864) { in = qkv_w; out = qwt; C = 3072; tb = bid - 4096; }
    else            { in = out_w; out = owt; C = 1024; tb = bid - 4864; }
    int ntc = C >> 6;
    int tr = tb / ntc, tc = tb % ntc;
    int r0 = tr * 64, c0 = tc * 64;
    for (int e = threadIdx.x; e < 4096; e += 256) {
        int r = e >> 6, c = e & 63;
        t[r][c] = (__bf16)in[(size_t)(r0 + r) * C + c0 + c];
    }
    __syncthreads();
    for (int e = threadIdx.x; e < 4096; e += 256) {
        int r = e >> 6, c = e & 63;
        out[(size_t)(c0 + r) * R + r0 + c] = t[c][r];
    }
}

// =============== 256x256 8-phase GEMM: C[M,N] = A[M,K] @ Bt[N,K]^T ===========
// THE validated configuration (393us total run: QKV 204us, 941 TF, MfmaUtil
// 41%, 0 bank conflicts, no spill). Six restructure attempts (one-barrier
// lookahead x2, persistent, lastit-branching, 128^2 tile, no-swizzle) all
// regressed — this schedule is the plain-HIP plateau for this kernel. Do not
// perturb the inner loop: in-phase ds_reads keep live ranges short (128 VGPR,
// no spill); branch-free loop with clamped junk prefetch on the final iter;
// counted VMC6 publishes at ph3/ph7; stores never interleave with the K-loop.
#define BARRIER() __builtin_amdgcn_s_barrier()
#define LGKM0()                                                     \
    do {                                                            \
        asm volatile("s_waitcnt lgkmcnt(0)" ::: "memory");          \
        __builtin_amdgcn_sched_barrier(0);                          \
    } while (0)
#define VMC6() asm volatile("s_waitcnt vmcnt(6)" ::: "memory")
#define VMC0() asm volatile("s_waitcnt vmcnt(0)" ::: "memory")

// stage A half (mh=0/1): rows {mh*64 + wid*8} and {128 + mh*64 + wid*8}
#define ST_A(buf, mh, kt)                                                     \
    do {                                                                      \
        int r0_ = (mh) * 64 + wid * 8;                                        \
        int r1_ = 128 + (mh) * 64 + wid * 8;                                  \
        gload16(Ab + (size_t)(r0_ + srow) * K + (kt) + sslot * 8,             \
                &lds[buf][0][r0_][0]);                                        \
        gload16(Ab + (size_t)(r1_ + srow) * K + (kt) + sslot * 8,             \
                &lds[buf][0][r1_][0]);                                        \
    } while (0)

// stage B half (nh=0/1)
#define ST_B(buf, nh, kt)                                                     \
    do {                                                                      \
        int r0_ = (wid >> 2) * 64 + (nh) * 32 + (wid & 3) * 8;                \
        int r1_ = r0_ + 128;                                                  \
        gload16(Bb + (size_t)(r0_ + srow) * K + (kt) + sslot * 8,             \
                &lds[buf][1][r0_][0]);                                        \
        gload16(Bb + (size_t)(r1_ + srow) * K + (kt) + sslot * 8,             \
                &lds[buf][1][r1_][0]);                                        \
    } while (0)

#define RD_A(buf, mh)                                                         \
    _Pragma("unroll") for (int mq = 0; mq < 4; ++mq)                          \
    _Pragma("unroll") for (int kk = 0; kk < 2; ++kk)                          \
        af[(mh) * 4 + mq][kk] = *(const bf16x8*)(                             \
            &lds[buf][0][wm * 128 + ((mh) * 4 + mq) * 16 + lrow]              \
                [(((kk << 2) + hi) ^ (lrow & 7)) * 8]);

#define RD_B(buf, nh)                                                         \
    _Pragma("unroll") for (int nq = 0; nq < 2; ++nq)                          \
    _Pragma("unroll") for (int kk = 0; kk < 2; ++kk)                          \
        bfr[(nh) * 2 + nq][kk] = *(const bf16x8*)(                            \
            &lds[buf][1][wn * 64 + ((nh) * 2 + nq) * 16 + lrow]               \
                [(((kk << 2) + hi) ^ (lrow & 7)) * 8]);

#define QUAD(mh, nh)                                                          \
    do {                                                                      \
        __builtin_amdgcn_s_setprio(1);                                        \
        _Pragma("unroll") for (int mq = 0; mq < 4; ++mq)                      \
        _Pragma("unroll") for (int nq = 0; nq < 2; ++nq)                      \
        _Pragma("unroll") for (int kk = 0; kk < 2; ++kk)                      \
            acc[(mh) * 4 + mq][(nh) * 2 + nq] =                               \
                MFMA16(af[(mh) * 4 + mq][kk], bfr[(nh) * 2 + nq][kk],         \
                       acc[(mh) * 4 + mq][(nh) * 2 + nq]);                    \
        __builtin_amdgcn_s_setprio(0);                                        \
    } while (0)

template <int OUTF32>
__global__ __launch_bounds__(512, 2) void gemm256(const __bf16* __restrict__ A,
                                                  const __bf16* __restrict__ Bt,
                                                  __bf16* __restrict__ Cb,
                                                  float* __restrict__ Cf,
                                                  const float* __restrict__ bias,
                                                  int M, int N, int K) {
    __shared__ __align__(16) __bf16 lds[2][2][256][64];
    const int tid = threadIdx.x;
    const int wid = tid >> 6, lane = tid & 63;
    const int lrow = lane & 15, hi = lane >> 4;
    const int wm = wid >> 2, wn = wid & 3;

    const int ntn = N >> 8;
    const int nwg = gridDim.x, bid = blockIdx.x;
    const int swz = (bid & 7) * (nwg >> 3) + (bid >> 3);
    const int tm = swz / ntn, tn = swz % ntn;

    const __bf16* Ab = A + (size_t)tm * 256 * K;
    const __bf16* Bb = Bt + (size_t)tn * 256 * K;
    const int srow = lane >> 3;              // row-within-8 for staging
    const int sslot = (lane & 7) ^ srow;     // inverse-swizzled 16B k-slot

    f32x4 acc[8][4];
#pragma unroll
    for (int m = 0; m < 8; ++m)
#pragma unroll
        for (int n = 0; n < 4; ++n) acc[m][n] = 0;

    bf16x8 af[8][2], bfr[4][2];

    // prologue: tile0 complete into buf0; tile1 AX,AY,BX into buf1 (14 loads)
    ST_A(0, 0, 0); ST_A(0, 1, 0); ST_B(0, 0, 0); ST_B(0, 1, 0);
    ST_A(1, 0, 64); ST_A(1, 1, 64); ST_B(1, 0, 64);
    VMC6();        // oldest 8 (= tile0) landed
    BARRIER();     // publish to all waves

    const int niter = K >> 7;   // 2 K-tiles per iteration
    for (int it = 0; it < niter; ++it) {
        const int kt1 = it * 128 + 64;
        const int ka = (it * 128 + 128 < K) ? it * 128 + 128 : K - 64;  // T+2 src
        const int kb = (kt1 + 128 < K) ? kt1 + 128 : K - 64;            // T+3 src

        // ph0: T0 quad(0,0) from buf0; stage BY(b1)
        RD_A(0, 0); RD_B(0, 0);
        ST_B(1, 1, kt1);
        BARRIER(); LGKM0(); QUAD(0, 0); BARRIER();
        // ph1: quad(1,0); stage AX(T+2)
        RD_A(0, 1);
        ST_A(0, 0, ka);
        BARRIER(); LGKM0(); QUAD(1, 0); BARRIER();
        // ph2: quad(0,1); stage AY(T+2)
        RD_B(0, 1);
        ST_A(0, 1, ka);
        BARRIER(); LGKM0(); QUAD(0, 1); BARRIER();
        // ph3: quad(1,1); stage BX(T+2); vmcnt(6) -> b1 landed
        ST_B(0, 0, ka);
        VMC6();
        BARRIER(); LGKM0(); QUAD(1, 1); BARRIER();
        // ph4: T1 quad(0,0) from buf1; stage BY(T+2)
        RD_A(1, 0); RD_B(1, 0);
        ST_B(0, 1, ka);
        BARRIER(); LGKM0(); QUAD(0, 0); BARRIER();
        // ph5: quad(1,0); stage AX(T+3)
        RD_A(1, 1);
        ST_A(1, 0, kb);
        BARRIER(); LGKM0(); QUAD(1, 0); BARRIER();
        // ph6: quad(0,1); stage AY(T+3)
        RD_B(1, 1);
        ST_A(1, 1, kb);
        BARRIER(); LGKM0(); QUAD(0, 1); BARRIER();
        // ph7: quad(1,1); stage BX(T+3); vmcnt(6) -> T+2 buf0 landed
        ST_B(1, 0, kb);
        VMC6();
        BARRIER(); LGKM0(); QUAD(1, 1); BARRIER();
    }

    VMC0();        // drain DMA before LDS goes out of scope
    BARRIER();

#pragma unroll
    for (int m = 0; m < 8; ++m)
#pragma unroll
        for (int n = 0; n < 4; ++n) {
            int row = tm * 256 + wm * 128 + m * 16 + hi * 4;
            int col = tn * 256 + wn * 64 + n * 16 + lrow;
#pragma unroll
            for (int r = 0; r < 4; ++r) {
                if constexpr (OUTF32)
                    Cf[(size_t)(row + r) * N + col] = acc[m][n][r] + bias[col];
                else
                    Cb[(size_t)(row + r) * N + col] = (__bf16)acc[m][n][r];
            }
        }
}

// ------------- fused masked attention v2, one block per (b, h) -------------
// Q and K fragments load DIRECTLY global->reg; only V LDS-staged (transposed)
// + per-wave Ps. One barrier total.
__global__ __launch_bounds__(256) void attn_kernel(const __bf16* __restrict__ qkv,
                                                   __bf16* __restrict__ aout) {
    constexpr int LDK = 72;
    __shared__ __bf16 VT[64 * LDK];   // [d][n]
    __shared__ __bf16 Ps[64 * LDK];   // [i][j], rows wr..wr+15 owned per wave

    const int b = blockIdx.x >> 4, h = blockIdx.x & 15;
    const int tid = threadIdx.x;
    const __bf16* base = qkv + (size_t)b * 60 * 3072 + h * 64;

    // zero VT pad cols n=60..63 (the only garbage that reaches arithmetic)
    VT[(tid >> 2) * LDK + 60 + (tid & 3)] = (__bf16)0.f;

    // stage V transposed: VT[d][n]
    for (int c = tid; c < 480; c += 256) {
        int n = c >> 3, d0 = (c & 7) * 8;
        bf16x8 v = *(const bf16x8*)(base + 2048 + (size_t)n * 3072 + d0);
#pragma unroll
        for (int j = 0; j < 8; ++j) VT[(d0 + j) * LDK + n] = v[j];
    }

    const int wid = tid >> 6, lane = tid & 63;
    const int lrow = lane & 15, hi = lane >> 4;
    const int wr = wid * 16;

    // Q A-frags direct from global
    bf16x8 aq[2];
#pragma unroll
    for (int kk = 0; kk < 2; ++kk)
        aq[kk] = *(const bf16x8*)(base + (size_t)(wr + lrow) * 3072 + kk * 32 + hi * 8);

    // S = Q @ K^T; K B-frags direct from global
    f32x4 s[4];
#pragma unroll
    for (int fi = 0; fi < 4; ++fi) s[fi] = 0;
#pragma unroll
    for (int kk = 0; kk < 2; ++kk)
#pragma unroll
        for (int fi = 0; fi < 4; ++fi) {
            bf16x8 bk = *(const bf16x8*)(base + 1024 +
                                         (size_t)(fi * 16 + lrow) * 3072 +
                                         kk * 32 + hi * 8);
            s[fi] = MFMA16(aq[kk], bk, s[fi]);
        }

    // masked softmax, rows i = wr + hi*4 + r, cols j = fi*16 + lrow
    const float scale = 0.125f;
#pragma unroll
    for (int r = 0; r < 4; ++r) {
        int i = wr + hi * 4 + r;
        float p[4];
        float mx = -3.0e38f;
#pragma unroll
        for (int fi = 0; fi < 4; ++fi) {
            int j = fi * 16 + lrow;
            float v = mask_ij(i, j) ? s[fi][r] * scale : -1.0e30f;
            p[fi] = v;
            mx = fmaxf(mx, v);
        }
#pragma unroll
        for (int off = 1; off <= 8; off <<= 1) mx = fmaxf(mx, __shfl_xor(mx, off));
        float se = 0.f;
#pragma unroll
        for (int fi = 0; fi < 4; ++fi) {
            p[fi] = __expf(p[fi] - mx);
            se += p[fi];
        }
#pragma unroll
        for (int off = 1; off <= 8; off <<= 1) se += __shfl_xor(se, off);
        float inv = 1.0f / se;
#pragma unroll
        for (int fi = 0; fi < 4; ++fi)
            Ps[i * LDK + fi * 16 + lrow] = (__bf16)(p[fi] * inv);
    }

    __syncthreads();   // VT staged (overlapped with QK^T + softmax)

    // O = P @ V
    f32x4 o[4];
#pragma unroll
    for (int fd = 0; fd < 4; ++fd) o[fd] = 0;
#pragma unroll
    for (int kk = 0; kk < 2; ++kk) {
        bf16x8 ap = *(const bf16x8*)(Ps + (wr + lrow) * LDK + kk * 32 + hi * 8);
#pragma unroll
        for (int fd = 0; fd < 4; ++fd) {
            bf16x8 bv = *(const bf16x8*)(VT + (fd * 16 + lrow) * LDK + kk * 32 + hi * 8);
            o[fd] = MFMA16(ap, bv, o[fd]);
        }
    }

#pragma unroll
    for (int fd = 0; fd < 4; ++fd)
#pragma unroll
        for (int r = 0; r < 4; ++r) {
            int i = wr + hi * 4 + r;
            if (i < 60)
                aout[(size_t)(b * 60 + i) * 1024 + h * 64 + fd * 16 + lrow] =
                    (__bf16)o[fd][r];
        }
}

extern "C" void kernel_launch(void* const* d_in, const int* in_sizes, int n_in,
                              void* d_out, int out_size, void* d_ws, size_t ws_size,
                              hipStream_t stream) {
    const float* x = (const float*)d_in[0];
    const float* qkv_w = (const float*)d_in[5];
    const float* out_w = (const float*)d_in[6];
    const float* out_b = (const float*)d_in[7];
    float* out = (float*)d_out;

    char* w = (char*)d_ws;
    __bf16* xb   = (__bf16*)w;                      // 30720*1024*2   = 62,914,560
    __bf16* qwt  = (__bf16*)(w + 62914560);         // 3072*1024*2    =  6,291,456
    __bf16* owt  = (__bf16*)(w + 69206016);         // 1024*1024*2    =  2,097,152
    __bf16* qkv  = (__bf16*)(w + 71303168);         // 30720*3072*2   = 188,743,680
    __bf16* aout = (__bf16*)(w + 260046848);        // 30720*1024*2   = 62,914,560

    // fused prep: cast x + transpose both weight matrices
    prep<<<dim3(5120), dim3(256), 0, stream>>>(x, xb, qkv_w, qwt, out_w, owt);

    // qkv = xb @ qkv_w : M=30720, N=3072, K=1024 -> 120x12 = 1440 blocks
    gemm256<0><<<dim3(1440), dim3(512), 0, stream>>>(xb, qwt, qkv, nullptr,
                                                     nullptr, 30720, 3072, 1024);
    // attention: one block per (b, h)
    attn_kernel<<<dim3(512 * 16), dim3(256), 0, stream>>>(qkv, aout);

    // out = aout @ out_w + out_b : M=30720, N=1024, K=1024 -> 120x4 = 480 blocks
    gemm256<1><<<dim3(480), dim3(512), 0, stream>>>(aout, owt, nullptr, out,
                                                    out_b, 30720, 1024, 1024);
}